// Round 1
// baseline (4760.617 us; speedup 1.0000x reference)
//
#include <hip/hip_runtime.h>
#include <hip/hip_bf16.h>

#define B_   16
#define NB   1024
#define NS   4096
#define C_   768
#define H_   12
#define DH   64
#define KTOP 128
#define CM   3072
#define EPSV 1e-5f

typedef __hip_bfloat16 bf16;

__device__ __forceinline__ float bf2f(unsigned short s){
  union{unsigned int u; float f;} v; v.u = ((unsigned int)s)<<16; return v.f;
}

template<typename T> __device__ __forceinline__ float4 load4(const T* p);
template<> __device__ __forceinline__ float4 load4<float>(const float* p){ return *(const float4*)p; }
template<> __device__ __forceinline__ float4 load4<bf16>(const bf16* p){
  ushort4 u = *(const ushort4*)p;
  return make_float4(bf2f(u.x), bf2f(u.y), bf2f(u.z), bf2f(u.w));
}

template<typename T> __device__ __forceinline__ void store4(T* p, float4 v);
template<> __device__ __forceinline__ void store4<float>(float* p, float4 v){ *(float4*)p = v; }
template<> __device__ __forceinline__ void store4<bf16>(bf16* p, float4 v){
  union{ ushort4 u; bf16 h[4]; } t;
  t.h[0] = __float2bfloat16(v.x); t.h[1] = __float2bfloat16(v.y);
  t.h[2] = __float2bfloat16(v.z); t.h[3] = __float2bfloat16(v.w);
  *(ushort4*)p = t.u;
}

__device__ __forceinline__ float gelu_exact(float x){
  return 0.5f * x * (1.0f + erff(x * 0.70710678118654752f));
}

// ---------------------------------------------------------------------------
// Generic tiled GEMM: out[M,N] = act(A[M,K] @ W[K,N] + bias [+ res[M,N]])
// 64x64 tile, BK=16, 256 threads, 4x4 micro-tile. M,N % 64 == 0, K % 16 == 0.
// ---------------------------------------------------------------------------
template<typename TIN, typename TOUT, int ACT, bool RES>
__global__ __launch_bounds__(256) void gemm_tile(
    const TIN* __restrict__ A, const float* __restrict__ W,
    const float* __restrict__ bias, const float* __restrict__ res,
    TOUT* __restrict__ out, int M, int N, int K)
{
  __shared__ float As[16][68];   // transposed: As[k][m]
  __shared__ float Bs[16][68];   // Bs[k][n]
  const int tid = threadIdx.x;
  const int tx = tid & 15, ty = tid >> 4;
  const int m0 = blockIdx.y * 64, n0 = blockIdx.x * 64;
  const int am = tid >> 2, ak = (tid & 3) * 4;
  const int bk = tid >> 4, bn = (tid & 15) * 4;
  float c[4][4] = {{0.f,0.f,0.f,0.f},{0.f,0.f,0.f,0.f},{0.f,0.f,0.f,0.f},{0.f,0.f,0.f,0.f}};

  for (int k0 = 0; k0 < K; k0 += 16){
    float4 a4 = load4<TIN>(A + (size_t)(m0+am)*K + (k0+ak));
    As[ak+0][am]=a4.x; As[ak+1][am]=a4.y; As[ak+2][am]=a4.z; As[ak+3][am]=a4.w;
    float4 b4 = *(const float4*)(W + (size_t)(k0+bk)*N + (n0+bn));
    *(float4*)&Bs[bk][bn] = b4;
    __syncthreads();
#pragma unroll
    for (int kk=0; kk<16; kk++){
      const float4 a = *(const float4*)&As[kk][ty*4];
      const float4 b = *(const float4*)&Bs[kk][tx*4];
      const float av[4] = {a.x,a.y,a.z,a.w};
      const float bw[4] = {b.x,b.y,b.z,b.w};
#pragma unroll
      for (int i=0;i<4;i++)
#pragma unroll
        for (int j=0;j<4;j++)
          c[i][j] = fmaf(av[i], bw[j], c[i][j]);
    }
    __syncthreads();
  }

  const float4 bv = *(const float4*)(bias + n0 + tx*4);
#pragma unroll
  for (int i=0;i<4;i++){
    const size_t row = (size_t)(m0 + ty*4 + i);
    float4 v = make_float4(c[i][0]+bv.x, c[i][1]+bv.y, c[i][2]+bv.z, c[i][3]+bv.w);
    if (RES){
      const float4 r = *(const float4*)(res + row*N + n0 + tx*4);
      v.x+=r.x; v.y+=r.y; v.z+=r.z; v.w+=r.w;
    }
    if (ACT==1){ v.x=gelu_exact(v.x); v.y=gelu_exact(v.y); v.z=gelu_exact(v.z); v.w=gelu_exact(v.w); }
    store4<TOUT>(out + row*N + n0 + tx*4, v);
  }
}

// ---------------------------------------------------------------------------
// Saliency: scores[b,i] = max_j dot(sampled[b,i,:], base[b,j,:]) / sqrt(C)
// fp32 chunk partials folded into fp64 accumulators for ranking stability.
// ---------------------------------------------------------------------------
__global__ __launch_bounds__(256) void saliency_max(
    const float* __restrict__ sampled, const float* __restrict__ base,
    float* __restrict__ scores, double* __restrict__ dscores)
{
  const int b = blockIdx.y, it = blockIdx.x;
  __shared__ float As[16][68];
  __shared__ float Bs[16][68];
  __shared__ double redd[64][17];
  const int tid = threadIdx.x;
  const int tx = tid & 15, ty = tid >> 4;
  const int am = tid >> 2, ak = (tid & 3) * 4;
  const float* Ab = sampled + (size_t)b*NS*C_ + (size_t)it*64*C_;
  const float* Bb = base + (size_t)b*NB*C_;
  double rmax[4] = {-1e300,-1e300,-1e300,-1e300};

  for (int jt = 0; jt < NB/64; jt++){
    double acc[4][4] = {{0,0,0,0},{0,0,0,0},{0,0,0,0},{0,0,0,0}};
    for (int k0 = 0; k0 < C_; k0 += 16){
      float4 a4 = *(const float4*)(Ab + (size_t)am*C_ + (k0+ak));
      As[ak+0][am]=a4.x; As[ak+1][am]=a4.y; As[ak+2][am]=a4.z; As[ak+3][am]=a4.w;
      float4 b4 = *(const float4*)(Bb + (size_t)(jt*64+am)*C_ + (k0+ak));
      Bs[ak+0][am]=b4.x; Bs[ak+1][am]=b4.y; Bs[ak+2][am]=b4.z; Bs[ak+3][am]=b4.w;
      __syncthreads();
      float pc[4][4] = {{0.f,0.f,0.f,0.f},{0.f,0.f,0.f,0.f},{0.f,0.f,0.f,0.f},{0.f,0.f,0.f,0.f}};
#pragma unroll
      for (int kk=0; kk<16; kk++){
        const float4 a = *(const float4*)&As[kk][ty*4];
        const float4 bb = *(const float4*)&Bs[kk][tx*4];
        const float av[4] = {a.x,a.y,a.z,a.w};
        const float bw[4] = {bb.x,bb.y,bb.z,bb.w};
#pragma unroll
        for (int i=0;i<4;i++)
#pragma unroll
          for (int j=0;j<4;j++)
            pc[i][j] = fmaf(av[i], bw[j], pc[i][j]);
      }
      __syncthreads();
#pragma unroll
      for (int i=0;i<4;i++)
#pragma unroll
        for (int j=0;j<4;j++)
          acc[i][j] += (double)pc[i][j];
    }
#pragma unroll
    for (int i=0;i<4;i++){
      double m = fmax(fmax(acc[i][0],acc[i][1]), fmax(acc[i][2],acc[i][3]));
      rmax[i] = fmax(rmax[i], m);
    }
  }
#pragma unroll
  for (int i=0;i<4;i++) redd[ty*4+i][tx] = rmax[i];
  __syncthreads();
  if (tid < 64){
    double m = redd[tid][0];
#pragma unroll
    for (int t=1;t<16;t++) m = fmax(m, redd[tid][t]);
    const double RSC = 0.036084391824351615; // 1/sqrt(768)
    double sc = m * RSC;
    scores[(size_t)b*NS + it*64 + tid] = (float)sc;
    dscores[(size_t)b*NS + it*64 + tid] = sc;
  }
}

// ---------------------------------------------------------------------------
// Top-k (iterative argmax, k=128) on fp64 scores; tie-break = lowest index.
// One block per batch.
// ---------------------------------------------------------------------------
__global__ __launch_bounds__(256) void topk_kernel(
    const double* __restrict__ dsc, float* __restrict__ topk_f, int* __restrict__ topk_i)
{
  const int b = blockIdx.x, tid = threadIdx.x;
  __shared__ double vals[NS];
  __shared__ int sel[KTOP];
  __shared__ double wv_s[4]; __shared__ int wi_s[4];
  for (int e=0;e<NS/256;e++) vals[e*256+tid] = dsc[(size_t)b*NS + e*256+tid];
  __syncthreads();
  for (int iter=0; iter<KTOP; iter++){
    double bv = -1e300; int bi = 0x7fffffff;
    for (int e=0;e<NS/256;e++){
      int idx = e*256+tid; double v = vals[idx];
      if (v > bv){ bv=v; bi=idx; }
    }
    for (int off=32; off>=1; off>>=1){
      double ov = __shfl_down(bv, off);
      int    oi = __shfl_down(bi, off);
      if (ov > bv || (ov == bv && oi < bi)){ bv=ov; bi=oi; }
    }
    const int lane = tid & 63, w = tid >> 6;
    if (lane==0){ wv_s[w]=bv; wi_s[w]=bi; }
    __syncthreads();
    if (tid==0){
      double fv = wv_s[0]; int fi = wi_s[0];
      for (int t=1;t<4;t++) if (wv_s[t] > fv || (wv_s[t]==fv && wi_s[t]<fi)){ fv=wv_s[t]; fi=wi_s[t]; }
      sel[iter] = fi; vals[fi] = -1e300;
    }
    __syncthreads();
  }
  if (tid < KTOP){
    topk_f[(size_t)b*KTOP + tid] = (float)sel[tid];
    topk_i[b*KTOP + tid] = sel[tid];
  }
}

__global__ __launch_bounds__(192) void gather_kernel(
    const float* __restrict__ sampled, const int* __restrict__ topk_i, float* __restrict__ sel)
{
  const int blk = blockIdx.x; const int b = blk >> 7, kk = blk & 127;
  const int idx = topk_i[b*KTOP + kk];
  const float4* src = (const float4*)(sampled + ((size_t)b*NS + idx)*C_);
  float4* dst = (float4*)(sel + ((size_t)b*KTOP + kk)*C_);
  dst[threadIdx.x] = src[threadIdx.x];
}

// ---------------------------------------------------------------------------
// Attention part 1: logits = q k^T / 8, softmax rows -> attn output.
// Block = (qtile of 64 rows, head, batch). 256 threads: ty=rows/8, tx=keys/4.
// ---------------------------------------------------------------------------
__global__ __launch_bounds__(256) void attn_softmax(
    const bf16* __restrict__ q, const float* __restrict__ kbuf, float* __restrict__ attn)
{
  const int qt = blockIdx.x, h = blockIdx.y, b = blockIdx.z;
  __shared__ float As[16][68];    // q: As[k][row]
  __shared__ float Bs[16][132];   // k: Bs[k][key]
  const int tid = threadIdx.x;
  const int tx = tid & 31, ty = tid >> 5;
  const int am = tid >> 2, ak = (tid & 3)*4;
  const int bm = tid >> 1, bk = (tid & 1)*8;
  float c[8][4] = {{0.f,0.f,0.f,0.f},{0.f,0.f,0.f,0.f},{0.f,0.f,0.f,0.f},{0.f,0.f,0.f,0.f},
                   {0.f,0.f,0.f,0.f},{0.f,0.f,0.f,0.f},{0.f,0.f,0.f,0.f},{0.f,0.f,0.f,0.f}};

  for (int k0 = 0; k0 < DH; k0 += 16){
    float4 a4 = load4<bf16>(q + ((size_t)(b*NB + qt*64 + am))*C_ + h*DH + k0 + ak);
    As[ak+0][am]=a4.x; As[ak+1][am]=a4.y; As[ak+2][am]=a4.z; As[ak+3][am]=a4.w;
    const float* kp = kbuf + ((size_t)(b*KTOP + bm))*C_ + h*DH + k0 + bk;
    float4 b40 = *(const float4*)(kp);
    float4 b41 = *(const float4*)(kp + 4);
    Bs[bk+0][bm]=b40.x; Bs[bk+1][bm]=b40.y; Bs[bk+2][bm]=b40.z; Bs[bk+3][bm]=b40.w;
    Bs[bk+4][bm]=b41.x; Bs[bk+5][bm]=b41.y; Bs[bk+6][bm]=b41.z; Bs[bk+7][bm]=b41.w;
    __syncthreads();
#pragma unroll
    for (int kk=0; kk<16; kk++){
      const float4 a0 = *(const float4*)&As[kk][ty*8];
      const float4 a1 = *(const float4*)&As[kk][ty*8+4];
      const float4 bb = *(const float4*)&Bs[kk][tx*4];
      const float av[8] = {a0.x,a0.y,a0.z,a0.w,a1.x,a1.y,a1.z,a1.w};
      const float bw[4] = {bb.x,bb.y,bb.z,bb.w};
#pragma unroll
      for (int i=0;i<8;i++)
#pragma unroll
        for (int j=0;j<4;j++)
          c[i][j] = fmaf(av[i], bw[j], c[i][j]);
    }
    __syncthreads();
  }

  const float scale = 0.125f; // 1/sqrt(64)
  const size_t obase = (((size_t)b*H_ + h)*NB + (size_t)qt*64)*KTOP;
#pragma unroll
  for (int i=0;i<8;i++){
    float l[4];
#pragma unroll
    for (int j=0;j<4;j++) l[j] = c[i][j]*scale;
    float m = fmaxf(fmaxf(l[0],l[1]), fmaxf(l[2],l[3]));
    for (int off=16; off>=1; off>>=1) m = fmaxf(m, __shfl_xor(m, off, 32));
    float p[4]; float s = 0.f;
#pragma unroll
    for (int j=0;j<4;j++){ p[j] = expf(l[j]-m); s += p[j]; }
    for (int off=16; off>=1; off>>=1) s += __shfl_xor(s, off, 32);
    const float inv = 1.0f / s;
    float4 o = make_float4(p[0]*inv, p[1]*inv, p[2]*inv, p[3]*inv);
    *(float4*)(attn + obase + (size_t)(ty*8+i)*KTOP + tx*4) = o;
  }
}

// ---------------------------------------------------------------------------
// Attention part 2: attended[b,row,h*64+d] = attn[b,h,row,:] @ v[b,:,h*64+d]
// ---------------------------------------------------------------------------
__global__ __launch_bounds__(256) void attn_pv(
    const float* __restrict__ attn, const float* __restrict__ vbuf, bf16* __restrict__ attout)
{
  const int qt = blockIdx.x, h = blockIdx.y, b = blockIdx.z;
  __shared__ float As[16][68];   // attn: As[k][row]
  __shared__ float Bs[16][68];   // v: Bs[k][d]
  const int tid = threadIdx.x;
  const int tx = tid & 15, ty = tid >> 4;
  const int am = tid >> 2, ak = (tid & 3)*4;
  const int bk = tid >> 4, bn = (tid & 15)*4;
  const float* Ab = attn + (((size_t)b*H_ + h)*NB + (size_t)qt*64)*KTOP;
  float c[4][4] = {{0.f,0.f,0.f,0.f},{0.f,0.f,0.f,0.f},{0.f,0.f,0.f,0.f},{0.f,0.f,0.f,0.f}};

  for (int k0 = 0; k0 < KTOP; k0 += 16){
    float4 a4 = *(const float4*)(Ab + (size_t)am*KTOP + k0 + ak);
    As[ak+0][am]=a4.x; As[ak+1][am]=a4.y; As[ak+2][am]=a4.z; As[ak+3][am]=a4.w;
    float4 b4 = *(const float4*)(vbuf + ((size_t)(b*KTOP + k0 + bk))*C_ + h*DH + bn);
    *(float4*)&Bs[bk][bn] = b4;
    __syncthreads();
#pragma unroll
    for (int kk=0; kk<16; kk++){
      const float4 a = *(const float4*)&As[kk][ty*4];
      const float4 bb = *(const float4*)&Bs[kk][tx*4];
      const float av[4] = {a.x,a.y,a.z,a.w};
      const float bw[4] = {bb.x,bb.y,bb.z,bb.w};
#pragma unroll
      for (int i=0;i<4;i++)
#pragma unroll
        for (int j=0;j<4;j++)
          c[i][j] = fmaf(av[i], bw[j], c[i][j]);
    }
    __syncthreads();
  }
#pragma unroll
  for (int i=0;i<4;i++){
    float4 v = make_float4(c[i][0], c[i][1], c[i][2], c[i][3]);
    store4<bf16>(attout + ((size_t)(b*NB + qt*64 + ty*4 + i))*C_ + h*DH + tx*4, v);
  }
}

// ---------------------------------------------------------------------------
// LayerNorm over C=768. One block per row; optional second input (residual).
// ---------------------------------------------------------------------------
__global__ __launch_bounds__(256) void ln_kernel(
    const float* __restrict__ inA, const float* __restrict__ inB,
    const float* __restrict__ g, const float* __restrict__ bb, float* __restrict__ out)
{
  const int row = blockIdx.x, tid = threadIdx.x;
  const size_t base = (size_t)row * C_;
  float x[3];
#pragma unroll
  for (int e=0;e<3;e++){
    const int idx = e*256 + tid;
    x[e] = inA[base+idx] + (inB ? inB[base+idx] : 0.f);
  }
  float s1 = x[0]+x[1]+x[2];
  float s2 = x[0]*x[0]+x[1]*x[1]+x[2]*x[2];
  for (int off=32; off>=1; off>>=1){ s1 += __shfl_down(s1,off); s2 += __shfl_down(s2,off); }
  __shared__ float a1[4], a2[4], st[2];
  const int lane = tid & 63, w = tid >> 6;
  if (lane==0){ a1[w]=s1; a2[w]=s2; }
  __syncthreads();
  if (tid==0){
    float t1 = a1[0]+a1[1]+a1[2]+a1[3];
    float t2 = a2[0]+a2[1]+a2[2]+a2[3];
    float mu = t1 * (1.0f/C_);
    float var = t2 * (1.0f/C_) - mu*mu;
    st[0]=mu; st[1]=rsqrtf(var + EPSV);
  }
  __syncthreads();
  const float mu = st[0], rs = st[1];
#pragma unroll
  for (int e=0;e<3;e++){
    const int idx = e*256+tid;
    out[base+idx] = (x[e]-mu)*rs*g[idx] + bb[idx];
  }
}

// ---------------------------------------------------------------------------
extern "C" void kernel_launch(void* const* d_in, const int* in_sizes, int n_in,
                              void* d_out, int out_size, void* d_ws, size_t ws_size,
                              hipStream_t stream)
{
  const float* base    = (const float*)d_in[0];
  const float* sampled = (const float*)d_in[1];
  const float* Wq = (const float*)d_in[2];  const float* bq = (const float*)d_in[3];
  const float* Wk = (const float*)d_in[4];  const float* bk = (const float*)d_in[5];
  const float* Wv = (const float*)d_in[6];  const float* bv = (const float*)d_in[7];
  const float* Wo = (const float*)d_in[8];  const float* bo = (const float*)d_in[9];
  const float* g1 = (const float*)d_in[10]; const float* b1 = (const float*)d_in[11];
  const float* g2 = (const float*)d_in[12]; const float* b2 = (const float*)d_in[13];
  const float* Wm1 = (const float*)d_in[14]; const float* bm1 = (const float*)d_in[15];
  const float* Wm2 = (const float*)d_in[16]; const float* bm2 = (const float*)d_in[17];

  float* out = (float*)d_out;
  float* o_x      = out;                 // [16,1024,768]
  float* o_scores = out + 12582912;      // [16,4096]
  float* o_attn   = out + 12648448;      // [16,12,1024,128]
  float* o_topk   = out + 37814272;      // [16,128] (as float)
  float* o_sel    = out + 37816320;      // [16,128,768]

  char* ws = (char*)d_ws;
  int*    topk_i = (int*)   (ws);                 // 8 KB
  double* dscore = (double*)(ws + 8192);          // 512 KB
  float*  kbuf   = (float*) (ws + 532480);        // 6 MB
  float*  vbuf   = (float*) (ws + 6823936);       // 6 MB
  bf16*   qbuf   = (bf16*)  (ws + 13115392);      // 24 MB
  bf16*   attbuf = (bf16*)  (ws + 38281216);      // 24 MB
  float*  rbuf   = (float*) (ws + 63447040);      // 48 MB
  bf16*   hbuf   = (bf16*)  (ws + 113778688);     // 96 MB  (end ~204.5 MB)

  // 1) saliency scores (fp64-stable)
  saliency_max<<<dim3(NS/64, B_), 256, 0, stream>>>(sampled, base, o_scores, dscore);
  // 2) top-k
  topk_kernel<<<B_, 256, 0, stream>>>(dscore, o_topk, topk_i);
  // 3) gather selected
  gather_kernel<<<B_*KTOP, 192, 0, stream>>>(sampled, topk_i, o_sel);
  // 4-6) projections
  gemm_tile<float, bf16, 0, false><<<dim3(C_/64, (B_*NB)/64), 256, 0, stream>>>(base, Wq, bq, nullptr, qbuf, B_*NB, C_, C_);
  gemm_tile<float, float, 0, false><<<dim3(C_/64, (B_*KTOP)/64), 256, 0, stream>>>(o_sel, Wk, bk, nullptr, kbuf, B_*KTOP, C_, C_);
  gemm_tile<float, float, 0, false><<<dim3(C_/64, (B_*KTOP)/64), 256, 0, stream>>>(o_sel, Wv, bv, nullptr, vbuf, B_*KTOP, C_, C_);
  // 7) logits + softmax -> attn output
  attn_softmax<<<dim3(NB/64, H_, B_), 256, 0, stream>>>(qbuf, kbuf, o_attn);
  // 8) attn @ v
  attn_pv<<<dim3(NB/64, H_, B_), 256, 0, stream>>>(o_attn, vbuf, attbuf);
  // 9) output projection + residual
  gemm_tile<bf16, float, 0, true><<<dim3(C_/64, (B_*NB)/64), 256, 0, stream>>>(attbuf, Wo, bo, base, rbuf, B_*NB, C_, C_);
  // 10) LN1 -> x1 (stored in o_x)
  ln_kernel<<<B_*NB, 256, 0, stream>>>(rbuf, nullptr, g1, b1, o_x);
  // 11) MLP up + GELU
  gemm_tile<float, bf16, 1, false><<<dim3(CM/64, (B_*NB)/64), 256, 0, stream>>>(o_x, Wm1, bm1, nullptr, hbuf, B_*NB, CM, C_);
  // 12) MLP down
  gemm_tile<bf16, float, 0, false><<<dim3(C_/64, (B_*NB)/64), 256, 0, stream>>>(hbuf, Wm2, bm2, nullptr, rbuf, B_*NB, C_, CM);
  // 13) LN2 (x1 + h) -> final x (in-place over o_x)
  ln_kernel<<<B_*NB, 256, 0, stream>>>(rbuf, o_x, g2, b2, o_x);
}